// Round 10
// baseline (176.553 us; speedup 1.0000x reference)
//
#include <hip/hip_runtime.h>
#include <stdint.h>

typedef unsigned short u16;
typedef unsigned int   u32;
typedef __attribute__((ext_vector_type(8)))  short short8;
typedef __attribute__((ext_vector_type(4)))  float f32x4;
typedef __attribute__((ext_vector_type(16))) float f32x16;

#define NTOK 4096
#define LOG2E 1.44269504088896340736f
#define QS    (0.125f * LOG2E)

// round-to-nearest-even f32 -> bf16
__device__ __forceinline__ u16 f2bf(float f) {
    u32 u = __builtin_bit_cast(u32, f);
    u += 0x7fffu + ((u >> 16) & 1u);
    return (u16)(u >> 16);
}
__device__ __forceinline__ float bf2f(u16 v) {
    return __builtin_bit_cast(float, (u32)v << 16);
}
// pack two positive floats to bf16 pair (round-half-up), low half = a. 3 VALU ops.
__device__ __forceinline__ u32 pk_hu(float a, float b) {
    u32 ua = __builtin_bit_cast(u32, a) + 0x8000u;
    u32 ub = __builtin_bit_cast(u32, b) + 0x8000u;
    return __builtin_amdgcn_perm(ub, ua, 0x07060302);  // {ub.hi16, ua.hi16}
}
__device__ __forceinline__ f32x16 zero16() {
    f32x16 v;
#pragma unroll
    for (int i = 0; i < 16; ++i) v[i] = 0.f;
    return v;
}

#define MFMA16x32 __builtin_amdgcn_mfma_f32_16x16x32_bf16
#define MFMA32x16 __builtin_amdgcn_mfma_f32_32x32x16_bf16

// ---------------- kernel 1: QKV projection via MFMA (frozen from R9) ----------------
// V tiles packed with token axis permuted to the 32x32 MFMA D-layout row order
// (slot = token with bits 2<->3 swapped): attn's exp'd S D-regs ARE the PV B-operand.
__global__ __launch_bounds__(256) void qkv_mfma4(
    const float* __restrict__ x,
    const float* __restrict__ wq, const float* __restrict__ bq,
    const float* __restrict__ wk, const float* __restrict__ bk,
    const float* __restrict__ wv, const float* __restrict__ bv,
    u16* __restrict__ Q, u16* __restrict__ K, u16* __restrict__ Vp)
{
    __shared__ __align__(16) u16 Wl[3 * 64 * 72];
    __shared__ __align__(16) u16 Xl[64 * 64];
    const int tid  = threadIdx.x;
    const int b    = blockIdx.x & 7;
    const int slab = blockIdx.x >> 3;
    const int n0   = slab << 6;
    const int wave = tid >> 6;
    const int lane = tid & 63;
    const int quad = lane >> 4;
    const int l15  = lane & 15;

#pragma unroll
    for (int j = 0; j < 12; ++j) {
        const float* src = (j < 4) ? wq : (j < 8) ? wk : wv;
        const float sc = (j < 4) ? QS : 1.0f;
        const int idx = (j & 3) * 1024 + tid * 4;
        const float4 v = *(const float4*)(src + idx);
        uint2 pk;
        pk.x = (u32)f2bf(v.x * sc) | ((u32)f2bf(v.y * sc) << 16);
        pk.y = (u32)f2bf(v.z * sc) | ((u32)f2bf(v.w * sc) << 16);
        *(uint2*)&Wl[(j >> 2) * 4608 + (idx >> 6) * 72 + (idx & 63)] = pk;
    }

    float4 xs[4];
#pragma unroll
    for (int g = 0; g < 4; ++g) {
        const int ch = g * 16 + wave * 4 + quad;
        xs[g] = *(const float4*)(x + ((size_t)(b * 64 + ch)) * NTOK + n0 + l15 * 4);
    }
#pragma unroll
    for (int g = 0; g < 4; ++g) {
        const int ch = g * 16 + wave * 4 + quad;
        const float vv[4] = {xs[g].x, xs[g].y, xs[g].z, xs[g].w};
#pragma unroll
        for (int e = 0; e < 4; ++e) {
            const int tok = l15 * 4 + e;
            Xl[tok * 64 + (((ch >> 3) ^ (tok & 7)) & 7) * 8 + (ch & 7)] = f2bf(vv[e]);
        }
    }
    __syncthreads();

    const int row0 = wave * 16 + l15;
    short8 xf[2];
#pragma unroll
    for (int kk = 0; kk < 2; ++kk)
        xf[kk] = *(const short8*)&Xl[row0 * 64 + (((kk * 4 + quad) ^ (row0 & 7)) & 7) * 8];

    const size_t tokbase = (size_t)b * NTOK + n0 + wave * 16;

#pragma unroll
    for (int mat = 0; mat < 2; ++mat) {
        const float* bias = (mat == 0) ? bq : bk;
        const float bsc = (mat == 0) ? QS : 1.0f;
#pragma unroll
        for (int mt = 0; mt < 4; ++mt) {
            const u16* wr = &Wl[mat * 4608 + (mt * 16 + l15) * 72 + quad * 8];
            const short8 wf0 = *(const short8*)(wr);
            const short8 wf1 = *(const short8*)(wr + 32);
            f32x4 acc = {0.f, 0.f, 0.f, 0.f};
            acc = MFMA16x32(wf0, xf[0], acc, 0, 0, 0);
            acc = MFMA16x32(wf1, xf[1], acc, 0, 0, 0);
            const float4 b4 = *(const float4*)(bias + mt * 16 + quad * 4);
            uint2 pk;
            pk.x = (u32)f2bf(acc[0] + b4.x * bsc) | ((u32)f2bf(acc[1] + b4.y * bsc) << 16);
            pk.y = (u32)f2bf(acc[2] + b4.z * bsc) | ((u32)f2bf(acc[3] + b4.w * bsc) << 16);
            u16* dst = (mat == 0) ? Q : K;
            *(uint2*)(dst + (tokbase + l15) * 64 + mt * 16 + quad * 4) = pk;
        }
    }

    __syncthreads();
    u16* Vl = Xl;
    const int tok = wave * 16 + l15;
#pragma unroll
    for (int mt = 0; mt < 4; ++mt) {
        const u16* wr = &Wl[2 * 4608 + (mt * 16 + l15) * 72 + quad * 8];
        const short8 wf0 = *(const short8*)(wr);
        const short8 wf1 = *(const short8*)(wr + 32);
        f32x4 acc = {0.f, 0.f, 0.f, 0.f};
        acc = MFMA16x32(wf0, xf[0], acc, 0, 0, 0);
        acc = MFMA16x32(wf1, xf[1], acc, 0, 0, 0);
        const float4 b4 = *(const float4*)(bv + mt * 16 + quad * 4);
        const float o[4] = {acc[0] + b4.x, acc[1] + b4.y, acc[2] + b4.z, acc[3] + b4.w};
#pragma unroll
        for (int r = 0; r < 4; ++r) {
            const int d = mt * 16 + quad * 4 + r;
            Vl[d * 64 + (((tok >> 3) ^ ((d >> 1) & 7)) & 7) * 8 + (tok & 7)] = f2bf(o[r]);
        }
    }
    __syncthreads();

#pragma unroll
    for (int dd = 0; dd < 4; ++dd) {
        const int d2   = (tid >> 4) + dd * 16;
        const int tok0 = (tid & 15) * 4;
        const int slot = ((tok0 >> 3) ^ ((d2 >> 1) & 7)) & 7;
        const uint2 v2 = *(const uint2*)&Vl[d2 * 64 + slot * 8 + (tok0 & 7)];
        const int gt  = slab * 2 + (tok0 >> 5);
        const int tl  = tok0 & 31;
        const int sl  = (tl & 0x13) | (((tl >> 2) & 1) << 3) | (((tl >> 3) & 1) << 2);
        *(uint2*)(Vp + (((size_t)b * 128 + gt) * 64 + d2) * 32 + sl) = v2;
    }
}

// ---------------- kernel 2: fused attention + mix + 2x2 pool ----------------
// grid 256 = oh(32) x b(8 low). Block 1024 = 16 waves = 4 Q-groups (h, 32 rows)
// x 4 KV-slices (s, 1024 tokens) -> 4 waves/SIMD (occupancy doubles vs R9,
// same grid so L2 K/V volume unchanged). Per-wave state ~115 regs < the 128
// cap a 16-wave block imposes. Single kf/vf buffer, in-place prefetch: kf(t+1)
// loads issue right after S-MFMAs consume kf(t) (~300 cyc distance), vf(t+1)
// after PV. K-loop is LDS-free + shuffle-free (V pre-permuted).
__global__ __launch_bounds__(1024, 4) void attn9(
    const u16* __restrict__ Q, const u16* __restrict__ K,
    const u16* __restrict__ Vp,
    const float* __restrict__ wm, const float* __restrict__ bm,
    float* __restrict__ out)
{
    __shared__ __align__(16) char smem[54272];
    const int tid  = threadIdx.x;
    const int wave = tid >> 6;
    const int lane = tid & 63;
    const int c31  = lane & 31;
    const int hw   = lane >> 5;
    const int quad = lane >> 4;
    const int l15  = lane & 15;
    const int h    = wave >> 2;          // Q group (32 rows), 0..3
    const int s    = wave & 3;           // KV slice (1024 tokens)
    const int b    = blockIdx.x & 7;
    const int oh   = blockIdx.x >> 3;
    const int n0   = oh * 128;

    // Q B-frags: lane (c31,hw) holds Q[qrow=h*32+c31][k=ks*16+hw*8+j]
    short8 qf[4];
#pragma unroll
    for (int ks = 0; ks < 4; ++ks)
        qf[ks] = *(const short8*)(Q + ((size_t)(b * NTOK + n0 + h * 32 + c31)) * 64
                                    + ks * 16 + hw * 8);

    const u16* Kb  = K + ((size_t)b * NTOK + s * 1024) * 64;
    const u16* Vbp = Vp + ((size_t)b * 128 + s * 32) * 2048;

    f32x16 O[2];                          // [mt ch-half], 32 acc
    O[0] = zero16();
    O[1] = zero16();
    float lp0 = 0.f, lp1 = 0.f;

    short8 kf[4], vf[4];
#pragma unroll
    for (int ks = 0; ks < 4; ++ks)
        kf[ks] = *(const short8*)(Kb + c31 * 64 + ks * 16 + hw * 8);
#pragma unroll
    for (int mk = 0; mk < 4; ++mk)
        vf[mk] = *(const short8*)(Vbp + ((mk >> 1) * 32 + c31) * 32 + (mk & 1) * 16 + hw * 8);

#pragma unroll 1
    for (int t = 0; t < 32; ++t) {
        // ---- S^T = K.Q^T ----
        f32x16 a = zero16();
        a = MFMA32x16(kf[0], qf[0], a, 0, 0, 0);
        a = MFMA32x16(kf[1], qf[1], a, 0, 0, 0);
        a = MFMA32x16(kf[2], qf[2], a, 0, 0, 0);
        a = MFMA32x16(kf[3], qf[3], a, 0, 0, 0);
        // in-place prefetch K(t+1): kf just consumed
        const int tn = (t + 1 < 32) ? t + 1 : 31;
        const u16* kt = Kb + (size_t)tn * 2048;
#pragma unroll
        for (int ks = 0; ks < 4; ++ks)
            kf[ks] = *(const short8*)(kt + c31 * 64 + ks * 16 + hw * 8);
        // ---- exp2 + pack (regs are already the PV B-frag; V pre-permuted) ----
        uint4 B0, B1;
        {
            float p0, p1;
            p0 = __builtin_amdgcn_exp2f(a[0]);  p1 = __builtin_amdgcn_exp2f(a[1]);
            B0.x = pk_hu(p0, p1); lp0 += p0 + p1;
            p0 = __builtin_amdgcn_exp2f(a[2]);  p1 = __builtin_amdgcn_exp2f(a[3]);
            B0.y = pk_hu(p0, p1); lp1 += p0 + p1;
            p0 = __builtin_amdgcn_exp2f(a[4]);  p1 = __builtin_amdgcn_exp2f(a[5]);
            B0.z = pk_hu(p0, p1); lp0 += p0 + p1;
            p0 = __builtin_amdgcn_exp2f(a[6]);  p1 = __builtin_amdgcn_exp2f(a[7]);
            B0.w = pk_hu(p0, p1); lp1 += p0 + p1;
            p0 = __builtin_amdgcn_exp2f(a[8]);  p1 = __builtin_amdgcn_exp2f(a[9]);
            B1.x = pk_hu(p0, p1); lp0 += p0 + p1;
            p0 = __builtin_amdgcn_exp2f(a[10]); p1 = __builtin_amdgcn_exp2f(a[11]);
            B1.y = pk_hu(p0, p1); lp1 += p0 + p1;
            p0 = __builtin_amdgcn_exp2f(a[12]); p1 = __builtin_amdgcn_exp2f(a[13]);
            B1.z = pk_hu(p0, p1); lp0 += p0 + p1;
            p0 = __builtin_amdgcn_exp2f(a[14]); p1 = __builtin_amdgcn_exp2f(a[15]);
            B1.w = pk_hu(p0, p1); lp1 += p0 + p1;
        }
        const short8 pb0 = __builtin_bit_cast(short8, B0);
        const short8 pb1 = __builtin_bit_cast(short8, B1);
        // ---- O += P.V ----
        O[0] = MFMA32x16(vf[0], pb0, O[0], 0, 0, 0);
        O[0] = MFMA32x16(vf[1], pb1, O[0], 0, 0, 0);
        O[1] = MFMA32x16(vf[2], pb0, O[1], 0, 0, 0);
        O[1] = MFMA32x16(vf[3], pb1, O[1], 0, 0, 0);
        // in-place prefetch V(t+1)
        const u16* vt = Vbp + (size_t)tn * 2048;
#pragma unroll
        for (int mk = 0; mk < 4; ++mk)
            vf[mk] = *(const short8*)(vt + ((mk >> 1) * 32 + c31) * 32 + (mk & 1) * 16 + hw * 8);
    }

    // ---- epilogue (K-loop is LDS-free: first LDS touch is here) ----
    float lp = lp0 + lp1;
    lp += __shfl_xor(lp, 32);            // combine half-wave token sets

    float* lpbuf = (float*)(smem + 52224);   // 16 waves x 32 f32
    if (hw == 0) lpbuf[(h * 4 + s) * 32 + c31] = lp;

    if (s != 0) {                         // bf16 O-partial sections [32 rows][68]
        u16* sec = (u16*)smem + (h * 3 + s - 1) * 2176;
#pragma unroll
        for (int mt = 0; mt < 2; ++mt)
#pragma unroll
            for (int r = 0; r < 16; ++r) {
                const int ch = mt * 32 + (r & 3) + 8 * (r >> 2) + 4 * hw;
                sec[c31 * 68 + ch] = f2bf(O[mt][r]);
            }
    }
    __syncthreads();   // B2: partials visible

    float rinv = 0.f;
    if (s == 0) {
        float sum = 0.f;
#pragma unroll
        for (int sx = 0; sx < 4; ++sx)
            sum += lpbuf[(h * 4 + sx) * 32 + c31];
        rinv = 1.0f / sum;
#pragma unroll
        for (int sx = 1; sx < 4; ++sx) {
            const u16* sec = (const u16*)smem + (h * 3 + sx - 1) * 2176;
#pragma unroll
            for (int mt = 0; mt < 2; ++mt)
#pragma unroll
                for (int r = 0; r < 16; ++r) {
                    const int ch = mt * 32 + (r & 3) + 8 * (r >> 2) + 4 * hw;
                    O[mt][r] += bf2f(sec[c31 * 68 + ch]);
                }
        }
    }
    // all waves: wm -> bf16 B-frags + bias (global reads overlap the reduction)
    const int rt = wave & 7;             // mix row-tile (16 rows)
    const int cH = wave >> 3;            // mix channel half (32 ch)
    short8 wB[2][2];
    float bb[2];
#pragma unroll
    for (int nt2 = 0; nt2 < 2; ++nt2) {
        const int d = cH * 32 + nt2 * 16 + l15;
        const float* wr = wm + (size_t)d * 64 + quad * 8;
        const float4 a0 = *(const float4*)(wr);
        const float4 a1 = *(const float4*)(wr + 4);
        const float4 c0 = *(const float4*)(wr + 32);
        const float4 c1 = *(const float4*)(wr + 36);
        ((u32*)&wB[nt2][0])[0] = (u32)f2bf(a0.x) | ((u32)f2bf(a0.y) << 16);
        ((u32*)&wB[nt2][0])[1] = (u32)f2bf(a0.z) | ((u32)f2bf(a0.w) << 16);
        ((u32*)&wB[nt2][0])[2] = (u32)f2bf(a1.x) | ((u32)f2bf(a1.y) << 16);
        ((u32*)&wB[nt2][0])[3] = (u32)f2bf(a1.z) | ((u32)f2bf(a1.w) << 16);
        ((u32*)&wB[nt2][1])[0] = (u32)f2bf(c0.x) | ((u32)f2bf(c0.y) << 16);
        ((u32*)&wB[nt2][1])[1] = (u32)f2bf(c0.z) | ((u32)f2bf(c0.w) << 16);
        ((u32*)&wB[nt2][1])[2] = (u32)f2bf(c1.x) | ((u32)f2bf(c1.y) << 16);
        ((u32*)&wB[nt2][1])[3] = (u32)f2bf(c1.z) | ((u32)f2bf(c1.w) << 16);
        bb[nt2] = bm[d];
    }
    __syncthreads();   // B3: section reads done; M0 may overlay [0,16K)

    if (s == 0) {      // normalize -> M0 bf16 (swizzled [row&31][ch]) at h*4KB
        u16* M0 = (u16*)smem + h * 2048;
#pragma unroll
        for (int mt = 0; mt < 2; ++mt)
#pragma unroll
            for (int r = 0; r < 16; ++r) {
                const int ch = mt * 32 + (r & 3) + 8 * (r >> 2) + 4 * hw;
                const float v = O[mt][r] * rinv;
                M0[c31 * 64 + (((ch >> 3) ^ (c31 & 7)) & 7) * 8 + (ch & 7)] = f2bf(v);
            }
    }
    __syncthreads();   // B4

    // mix: wave (rt,cH): rows rt*16+[0,16), out-channels cH*32+[0,32)
    const int row = rt * 16 + l15;
    const u16* M0r = (const u16*)smem + (row >> 5) * 2048;
    const int lr = row & 31;
    const short8 af0 = *(const short8*)&M0r[lr * 64 + ((quad ^ (lr & 7)) & 7) * 8];
    const short8 af1 = *(const short8*)&M0r[lr * 64 + (((4 + quad) ^ (lr & 7)) & 7) * 8];
    float* Mf = (float*)(smem + 16384);      // [128][68] fp32, disjoint from M0
#pragma unroll
    for (int nt2 = 0; nt2 < 2; ++nt2) {
        f32x4 acc = {0.f, 0.f, 0.f, 0.f};
        acc = MFMA16x32(af0, wB[nt2][0], acc, 0, 0, 0);
        acc = MFMA16x32(af1, wB[nt2][1], acc, 0, 0, 0);
#pragma unroll
        for (int r = 0; r < 4; ++r) {
            float v = acc[r] + bb[nt2];
            v = v > 0.f ? v : 0.f;
            Mf[(rt * 16 + quad * 4 + r) * 68 + cH * 32 + nt2 * 16 + l15] = v;
        }
    }
    __syncthreads();   // B5

    // 2x2 avg pool (== bilinear 2x downsample, half-pixel)
    const int ow = tid & 31;
    const int c0 = tid >> 5;             // 0..31
#pragma unroll
    for (int i = 0; i < 2; ++i) {
        const int c = c0 + i * 32;
        const float v = 0.25f * (Mf[(2 * ow) * 68 + c] + Mf[(2 * ow + 1) * 68 + c]
                               + Mf[(64 + 2 * ow) * 68 + c] + Mf[(65 + 2 * ow) * 68 + c]);
        out[((size_t)(b * 64 + c) * 32 + oh) * 32 + ow] = v;
    }
}

extern "C" void kernel_launch(void* const* d_in, const int* in_sizes, int n_in,
                              void* d_out, int out_size, void* d_ws, size_t ws_size,
                              hipStream_t stream) {
    (void)in_sizes; (void)n_in; (void)out_size; (void)ws_size;
    const float* x  = (const float*)d_in[0];
    const float* wq = (const float*)d_in[1];
    const float* bq = (const float*)d_in[2];
    const float* wk = (const float*)d_in[3];
    const float* bk = (const float*)d_in[4];
    const float* wv = (const float*)d_in[5];
    const float* bv = (const float*)d_in[6];
    const float* wm = (const float*)d_in[7];
    const float* bm = (const float*)d_in[8];

    // ws: Q bf16 [8][4096][64] | K bf16 [8][4096][64] | Vp bf16 [8][128][64][32] = 12 MB
    u16* Q  = (u16*)d_ws;
    u16* K  = Q + (size_t)8 * NTOK * 64;
    u16* Vp = K + (size_t)8 * NTOK * 64;

    qkv_mfma4<<<512, 256, 0, stream>>>(x, wq, bq, wk, bk, wv, bv, Q, K, Vp);
    attn9<<<256, 1024, 0, stream>>>(Q, K, Vp, wm, bm, (float*)d_out);
}

// Round 11
// 136.017 us; speedup vs baseline: 1.2980x; 1.2980x over previous
//
#include <hip/hip_runtime.h>
#include <stdint.h>

typedef unsigned short u16;
typedef unsigned int   u32;
typedef __attribute__((ext_vector_type(8)))  short short8;
typedef __attribute__((ext_vector_type(4)))  float f32x4;
typedef __attribute__((ext_vector_type(16))) float f32x16;

#define NTOK 4096
#define LOG2E 1.44269504088896340736f
#define QS    (0.125f * LOG2E)

// round-to-nearest-even f32 -> bf16
__device__ __forceinline__ u16 f2bf(float f) {
    u32 u = __builtin_bit_cast(u32, f);
    u += 0x7fffu + ((u >> 16) & 1u);
    return (u16)(u >> 16);
}
__device__ __forceinline__ float bf2f(u16 v) {
    return __builtin_bit_cast(float, (u32)v << 16);
}
// pack two positive floats to bf16 pair (round-half-up), low half = a. 3 VALU ops.
__device__ __forceinline__ u32 pk_hu(float a, float b) {
    u32 ua = __builtin_bit_cast(u32, a) + 0x8000u;
    u32 ub = __builtin_bit_cast(u32, b) + 0x8000u;
    return __builtin_amdgcn_perm(ub, ua, 0x07060302);  // {ub.hi16, ua.hi16}
}
__device__ __forceinline__ f32x16 zero16() {
    f32x16 v;
#pragma unroll
    for (int i = 0; i < 16; ++i) v[i] = 0.f;
    return v;
}

#define MFMA16x32 __builtin_amdgcn_mfma_f32_16x16x32_bf16
#define MFMA32x16 __builtin_amdgcn_mfma_f32_32x32x16_bf16

// ---------------- kernel 1: QKV projection via MFMA (v2) ----------------
// grid 256 = slabpair(32 of 128 tok) x b(8 low bits -> XCD affinity);
// block 512 = 8 waves, each owning 16 tokens. Weight staging amortized over
// 128 tokens (R7-R10 staged per 64). V packed to Vp with in-tile token axis
// permuted to the 32x32 MFMA D-layout row order (bits 2<->3 swapped).
__global__ __launch_bounds__(512, 2) void qkv2(
    const float* __restrict__ x,
    const float* __restrict__ wq, const float* __restrict__ bq,
    const float* __restrict__ wk, const float* __restrict__ bk,
    const float* __restrict__ wv, const float* __restrict__ bv,
    u16* __restrict__ Q, u16* __restrict__ K, u16* __restrict__ Vp)
{
    __shared__ __align__(16) u16 Wl[3 * 64 * 72];   // 27648 B, row stride 72 u16
    __shared__ __align__(16) u16 Xl[128 * 64];      // [tok 0..127][ch] bf16, swizzled 16B slots
    const int tid  = threadIdx.x;
    const int b    = blockIdx.x & 7;
    const int sp   = blockIdx.x >> 3;               // slab-pair 0..31
    const int n0   = sp << 7;                       // 128 tokens
    const int wave = tid >> 6;
    const int lane = tid & 63;
    const int quad = lane >> 4;
    const int l15  = lane & 15;

    // ---- stage weights: 512 threads x 6 float4 = 12288 floats = wq|wk|wv ----
#pragma unroll
    for (int j = 0; j < 6; ++j) {
        const int idx  = j * 2048 + tid * 4;
        const int mat  = idx >> 12;                 // 0,1,2
        const int ridx = idx & 4095;
        const float* src = (mat == 0) ? wq : (mat == 1) ? wk : wv;
        const float sc = (mat == 0) ? QS : 1.0f;
        const float4 v = *(const float4*)(src + ridx);
        uint2 pk;
        pk.x = (u32)f2bf(v.x * sc) | ((u32)f2bf(v.y * sc) << 16);
        pk.y = (u32)f2bf(v.z * sc) | ((u32)f2bf(v.w * sc) << 16);
        *(uint2*)&Wl[mat * 4608 + (ridx >> 6) * 72 + (ridx & 63)] = pk;
    }

    // ---- stage x: thread (ch = tid>>3, tg = tid&7) reads 4 float4 = 16 toks ----
    const int ch = tid >> 3;
    const int tg = tid & 7;
    float4 xs[4];
#pragma unroll
    for (int k = 0; k < 4; ++k)
        xs[k] = *(const float4*)(x + ((size_t)(b * 64 + ch)) * NTOK + n0 + tg * 16 + k * 4);
#pragma unroll
    for (int k = 0; k < 4; ++k) {
        const float vv[4] = {xs[k].x, xs[k].y, xs[k].z, xs[k].w};
#pragma unroll
        for (int e = 0; e < 4; ++e) {
            const int tok = tg * 16 + k * 4 + e;
            Xl[tok * 64 + (((ch >> 3) ^ (tok & 7)) & 7) * 8 + (ch & 7)] = f2bf(vv[e]);
        }
    }
    __syncthreads();

    // ---- MFMA phase: wave w -> tokens [16w, 16w+16) ----
    const int row0 = wave * 16 + l15;
    short8 xf[2];
#pragma unroll
    for (int kk = 0; kk < 2; ++kk)
        xf[kk] = *(const short8*)&Xl[row0 * 64 + (((kk * 4 + quad) ^ (row0 & 7)) & 7) * 8];

    const size_t tokbase = (size_t)b * NTOK + n0 + wave * 16;

#pragma unroll
    for (int mat = 0; mat < 2; ++mat) {
        const float* bias = (mat == 0) ? bq : bk;
        const float bsc = (mat == 0) ? QS : 1.0f;
#pragma unroll
        for (int mt = 0; mt < 4; ++mt) {
            const u16* wr = &Wl[mat * 4608 + (mt * 16 + l15) * 72 + quad * 8];
            const short8 wf0 = *(const short8*)(wr);
            const short8 wf1 = *(const short8*)(wr + 32);
            f32x4 acc = {0.f, 0.f, 0.f, 0.f};
            acc = MFMA16x32(wf0, xf[0], acc, 0, 0, 0);
            acc = MFMA16x32(wf1, xf[1], acc, 0, 0, 0);
            const float4 b4 = *(const float4*)(bias + mt * 16 + quad * 4);
            uint2 pk;
            pk.x = (u32)f2bf(acc[0] + b4.x * bsc) | ((u32)f2bf(acc[1] + b4.y * bsc) << 16);
            pk.y = (u32)f2bf(acc[2] + b4.z * bsc) | ((u32)f2bf(acc[3] + b4.w * bsc) << 16);
            u16* dst = (mat == 0) ? Q : K;
            *(uint2*)(dst + (tokbase + l15) * 64 + mt * 16 + quad * 4) = pk;
        }
    }

    // ---- V: compute, LDS transpose (reuse Xl as two 64-tok panels), packed store ----
    __syncthreads();                  // all xf reads done; Xl reusable
    u16* Vl = Xl;                     // [(d*2 + tok>>6)][tok&63] bf16 panels, swizzled
    const int tok = wave * 16 + l15;  // 0..127
    const int th  = tok >> 6;
    const int t64 = tok & 63;
#pragma unroll
    for (int mt = 0; mt < 4; ++mt) {
        const u16* wr = &Wl[2 * 4608 + (mt * 16 + l15) * 72 + quad * 8];
        const short8 wf0 = *(const short8*)(wr);
        const short8 wf1 = *(const short8*)(wr + 32);
        f32x4 acc = {0.f, 0.f, 0.f, 0.f};
        acc = MFMA16x32(wf0, xf[0], acc, 0, 0, 0);
        acc = MFMA16x32(wf1, xf[1], acc, 0, 0, 0);
        const float4 b4 = *(const float4*)(bv + mt * 16 + quad * 4);
        const float o[4] = {acc[0] + b4.x, acc[1] + b4.y, acc[2] + b4.z, acc[3] + b4.w};
#pragma unroll
        for (int r = 0; r < 4; ++r) {
            const int d = mt * 16 + quad * 4 + r;
            Vl[(d * 2 + th) * 64 + (((t64 >> 3) ^ ((d >> 1) & 7)) & 7) * 8 + (t64 & 7)] = f2bf(o[r]);
        }
    }
    __syncthreads();

    // packed, permuted store: 512 threads x 4 uint2 chunks (16 KB total)
#pragma unroll
    for (int dd = 0; dd < 4; ++dd) {
        const int id   = dd * 512 + tid;
        const int d2   = id >> 5;            // 0..63
        const int tokc = (id & 31) * 4;      // 0..124
        const int thc  = tokc >> 6;
        const int t64c = tokc & 63;
        const int slot = ((t64c >> 3) ^ ((d2 >> 1) & 7)) & 7;
        const uint2 v2 = *(const uint2*)&Vl[(d2 * 2 + thc) * 64 + slot * 8 + (t64c & 7)];
        const int gt = sp * 4 + (tokc >> 5);
        const int tl = tokc & 31;
        const int sl = (tl & 0x13) | (((tl >> 2) & 1) << 3) | (((tl >> 3) & 1) << 2);
        *(uint2*)(Vp + (((size_t)b * 128 + gt) * 64 + d2) * 32 + sl) = v2;
    }
}

// ---------------- kernel 2: fused attention + mix + 2x2 pool (R9 attn8, best known) ----------------
__global__ __launch_bounds__(512, 2) void attn8(
    const u16* __restrict__ Q, const u16* __restrict__ K,
    const u16* __restrict__ Vp,
    const float* __restrict__ wm, const float* __restrict__ bm,
    float* __restrict__ out)
{
    __shared__ __align__(16) char smem[54272];
    const int tid  = threadIdx.x;
    const int wave = tid >> 6;
    const int lane = tid & 63;
    const int c31  = lane & 31;
    const int hw   = lane >> 5;
    const int quad = lane >> 4;
    const int l15  = lane & 15;
    const int h    = wave >> 2;          // Q half (64 rows)
    const int s    = wave & 3;           // KV slice (1024 tokens)
    const int b    = blockIdx.x & 7;
    const int oh   = blockIdx.x >> 3;
    const int n0   = oh * 128;

    short8 qf[2][4];
#pragma unroll
    for (int nt = 0; nt < 2; ++nt)
#pragma unroll
        for (int ks = 0; ks < 4; ++ks)
            qf[nt][ks] = *(const short8*)(Q + ((size_t)(b * NTOK + n0 + h * 64 + nt * 32 + c31)) * 64
                                            + ks * 16 + hw * 8);

    const u16* Kb  = K + ((size_t)b * NTOK + s * 1024) * 64;
    const u16* Vbp = Vp + ((size_t)b * 128 + s * 32) * 2048;

    f32x16 O[2][2];
#pragma unroll
    for (int mt = 0; mt < 2; ++mt)
#pragma unroll
        for (int nt = 0; nt < 2; ++nt) O[mt][nt] = zero16();
    float lpa[2] = {0.f, 0.f};

    auto load_kv = [&](short8 (&kf)[4], short8 (&vf)[4], int t) {
        const int tc = (t < 32) ? t : 31;
        const u16* kt = Kb + (size_t)tc * 2048;
#pragma unroll
        for (int ks = 0; ks < 4; ++ks)
            kf[ks] = *(const short8*)(kt + c31 * 64 + ks * 16 + hw * 8);
        const u16* vt = Vbp + (size_t)tc * 2048;
#pragma unroll
        for (int mk = 0; mk < 4; ++mk)
            vf[mk] = *(const short8*)(vt + ((mk >> 1) * 32 + c31) * 32 + (mk & 1) * 16 + hw * 8);
    };

    auto S_compute = [&](f32x16 (&sv)[2], const short8 (&kf)[4]) {
#pragma unroll
        for (int nt = 0; nt < 2; ++nt) {
            f32x16 a = zero16();
            a = MFMA32x16(kf[0], qf[nt][0], a, 0, 0, 0);
            a = MFMA32x16(kf[1], qf[nt][1], a, 0, 0, 0);
            a = MFMA32x16(kf[2], qf[nt][2], a, 0, 0, 0);
            a = MFMA32x16(kf[3], qf[nt][3], a, 0, 0, 0);
            sv[nt] = a;
        }
    };

    auto tile_tail = [&](const f32x16 (&sv)[2], const short8 (&vf)[4]) {
#pragma unroll
        for (int nt = 0; nt < 2; ++nt) {
            float p[16];
#pragma unroll
            for (int r = 0; r < 16; ++r) p[r] = __builtin_amdgcn_exp2f(sv[nt][r]);
            lpa[nt] += (((p[0] + p[1]) + (p[2] + p[3])) + ((p[4] + p[5]) + (p[6] + p[7])))
                     + (((p[8] + p[9]) + (p[10] + p[11])) + ((p[12] + p[13]) + (p[14] + p[15])));
            uint4 B0, B1;
            B0.x = pk_hu(p[0],  p[1]);  B0.y = pk_hu(p[2],  p[3]);
            B0.z = pk_hu(p[4],  p[5]);  B0.w = pk_hu(p[6],  p[7]);
            B1.x = pk_hu(p[8],  p[9]);  B1.y = pk_hu(p[10], p[11]);
            B1.z = pk_hu(p[12], p[13]); B1.w = pk_hu(p[14], p[15]);
            const short8 pb0 = __builtin_bit_cast(short8, B0);
            const short8 pb1 = __builtin_bit_cast(short8, B1);
            O[0][nt] = MFMA32x16(vf[0], pb0, O[0][nt], 0, 0, 0);
            O[0][nt] = MFMA32x16(vf[1], pb1, O[0][nt], 0, 0, 0);
            O[1][nt] = MFMA32x16(vf[2], pb0, O[1][nt], 0, 0, 0);
            O[1][nt] = MFMA32x16(vf[3], pb1, O[1][nt], 0, 0, 0);
        }
    };

    short8 kfA[4], vfA[4], kfB[4], vfB[4];
    f32x16 svA[2], svB[2];
    load_kv(kfA, vfA, 0);
    load_kv(kfB, vfB, 1);
    S_compute(svA, kfA);

#pragma unroll 1
    for (int tt = 0; tt < 16; ++tt) {
        const int t0 = tt * 2;
        S_compute(svB, kfB);
        tile_tail(svA, vfA);
        load_kv(kfA, vfA, t0 + 2);
        S_compute(svA, kfA);
        tile_tail(svB, vfB);
        load_kv(kfB, vfB, t0 + 3);
    }

#pragma unroll
    for (int nt = 0; nt < 2; ++nt) lpa[nt] += __shfl_xor(lpa[nt], 32);

    float* lpbuf = (float*)(smem + 52224);
    if (hw == 0) {
#pragma unroll
        for (int nt = 0; nt < 2; ++nt)
            lpbuf[(h * 4 + s) * 64 + nt * 32 + c31] = lpa[nt];
    }
    if (s != 0) {
        u16* sec = (u16*)smem + (h * 3 + s - 1) * 4352;
#pragma unroll
        for (int mt = 0; mt < 2; ++mt)
#pragma unroll
            for (int nt = 0; nt < 2; ++nt)
#pragma unroll
                for (int r = 0; r < 16; ++r) {
                    const int ch = mt * 32 + (r & 3) + 8 * (r >> 2) + 4 * hw;
                    sec[(nt * 32 + c31) * 68 + ch] = f2bf(O[mt][nt][r]);
                }
    }
    __syncthreads();   // B2

    float rinv[2];
    if (s == 0) {
#pragma unroll
        for (int nt = 0; nt < 2; ++nt) {
            float sum = 0.f;
#pragma unroll
            for (int sx = 0; sx < 4; ++sx)
                sum += lpbuf[(h * 4 + sx) * 64 + nt * 32 + c31];
            rinv[nt] = 1.0f / sum;
        }
#pragma unroll
        for (int sx = 1; sx < 4; ++sx) {
            const u16* sec = (const u16*)smem + (h * 3 + sx - 1) * 4352;
#pragma unroll
            for (int mt = 0; mt < 2; ++mt)
#pragma unroll
                for (int nt = 0; nt < 2; ++nt)
#pragma unroll
                    for (int r = 0; r < 16; ++r) {
                        const int ch = mt * 32 + (r & 3) + 8 * (r >> 2) + 4 * hw;
                        O[mt][nt][r] += bf2f(sec[(nt * 32 + c31) * 68 + ch]);
                    }
        }
    }
    short8 wB[4][2];
    float bb[4];
#pragma unroll
    for (int nt = 0; nt < 4; ++nt) {
        const int d = nt * 16 + l15;
        const float* wr = wm + (size_t)d * 64 + quad * 8;
        const float4 a0 = *(const float4*)(wr);
        const float4 a1 = *(const float4*)(wr + 4);
        const float4 c0 = *(const float4*)(wr + 32);
        const float4 c1 = *(const float4*)(wr + 36);
        ((u32*)&wB[nt][0])[0] = (u32)f2bf(a0.x) | ((u32)f2bf(a0.y) << 16);
        ((u32*)&wB[nt][0])[1] = (u32)f2bf(a0.z) | ((u32)f2bf(a0.w) << 16);
        ((u32*)&wB[nt][0])[2] = (u32)f2bf(a1.x) | ((u32)f2bf(a1.y) << 16);
        ((u32*)&wB[nt][0])[3] = (u32)f2bf(a1.z) | ((u32)f2bf(a1.w) << 16);
        ((u32*)&wB[nt][1])[0] = (u32)f2bf(c0.x) | ((u32)f2bf(c0.y) << 16);
        ((u32*)&wB[nt][1])[1] = (u32)f2bf(c0.z) | ((u32)f2bf(c0.w) << 16);
        ((u32*)&wB[nt][1])[2] = (u32)f2bf(c1.x) | ((u32)f2bf(c1.y) << 16);
        ((u32*)&wB[nt][1])[3] = (u32)f2bf(c1.z) | ((u32)f2bf(c1.w) << 16);
        bb[nt] = bm[d];
    }
    __syncthreads();   // B3

    if (s == 0) {
        u16* M0 = (u16*)smem + h * 4096;
#pragma unroll
        for (int mt = 0; mt < 2; ++mt)
#pragma unroll
            for (int nt = 0; nt < 2; ++nt)
#pragma unroll
                for (int r = 0; r < 16; ++r) {
                    const int lr = nt * 32 + c31;
                    const int ch = mt * 32 + (r & 3) + 8 * (r >> 2) + 4 * hw;
                    const float v = O[mt][nt][r] * rinv[nt];
                    M0[lr * 64 + (((ch >> 3) ^ (lr & 7)) & 7) * 8 + (ch & 7)] = f2bf(v);
                }
    }
    __syncthreads();   // B4

    const u16* M0r = (const u16*)smem + (wave >> 2) * 4096;
    const int lr = (wave & 3) * 16 + l15;
    const short8 af0 = *(const short8*)&M0r[lr * 64 + ((quad ^ (lr & 7)) & 7) * 8];
    const short8 af1 = *(const short8*)&M0r[lr * 64 + (((4 + quad) ^ (lr & 7)) & 7) * 8];
    float* Mf = (float*)(smem + 16384);
#pragma unroll
    for (int nt = 0; nt < 4; ++nt) {
        f32x4 acc = {0.f, 0.f, 0.f, 0.f};
        acc = MFMA16x32(af0, wB[nt][0], acc, 0, 0, 0);
        acc = MFMA16x32(af1, wB[nt][1], acc, 0, 0, 0);
#pragma unroll
        for (int r = 0; r < 4; ++r) {
            float v = acc[r] + bb[nt];
            v = v > 0.f ? v : 0.f;
            Mf[(wave * 16 + quad * 4 + r) * 68 + nt * 16 + l15] = v;
        }
    }
    __syncthreads();   // B5

    const int ow = tid & 31;
    const int cb = (tid >> 5) & 15;
#pragma unroll
    for (int i = 0; i < 4; ++i) {
        const int c = cb + i * 16;
        const float v = 0.25f * (Mf[(2 * ow) * 68 + c] + Mf[(2 * ow + 1) * 68 + c]
                               + Mf[(64 + 2 * ow) * 68 + c] + Mf[(65 + 2 * ow) * 68 + c]);
        out[((size_t)(b * 64 + c) * 32 + oh) * 32 + ow] = v;
    }
}

extern "C" void kernel_launch(void* const* d_in, const int* in_sizes, int n_in,
                              void* d_out, int out_size, void* d_ws, size_t ws_size,
                              hipStream_t stream) {
    (void)in_sizes; (void)n_in; (void)out_size; (void)ws_size;
    const float* x  = (const float*)d_in[0];
    const float* wq = (const float*)d_in[1];
    const float* bq = (const float*)d_in[2];
    const float* wk = (const float*)d_in[3];
    const float* bk = (const float*)d_in[4];
    const float* wv = (const float*)d_in[5];
    const float* bv = (const float*)d_in[6];
    const float* wm = (const float*)d_in[7];
    const float* bm = (const float*)d_in[8];

    // ws: Q bf16 [8][4096][64] | K bf16 [8][4096][64] | Vp bf16 [8][128][64][32] = 12 MB
    u16* Q  = (u16*)d_ws;
    u16* K  = Q + (size_t)8 * NTOK * 64;
    u16* Vp = K + (size_t)8 * NTOK * 64;

    qkv2<<<256, 512, 0, stream>>>(x, wq, bq, wk, bk, wv, bv, Q, K, Vp);
    attn8<<<256, 512, 0, stream>>>(Q, K, Vp, wm, bm, (float*)d_out);
}